// Round 10
// baseline (182.557 us; speedup 1.0000x reference)
//
#include <hip/hip_runtime.h>
#include <hip/hip_bf16.h>
#include <hip/hip_cooperative_groups.h>

namespace cg = cooperative_groups;

#define DIM      512
#define EDIM     1024
#define OUTD     512
#define BATCH    4
#define LSEQ     4096
#define MROWS    (BATCH * LSEQ)   // 16384

typedef __attribute__((ext_vector_type(8))) __bf16 bf16x8;
typedef __attribute__((ext_vector_type(4))) float  f32x4;

static __device__ __forceinline__ ushort f2b(float f) {
    uint x = __float_as_uint(f);
    x += 0x7fff + ((x >> 16) & 1);           // round-to-nearest-even
    return (ushort)(x >> 16);
}
static __device__ __forceinline__ float sigmoidf(float x) {
    return 1.0f / (1.0f + expf(-x));
}

// ------------------------------------------------- prep + emb->bf16 -------
// blocks [0,8192): convert emb fp32 -> bf16 (float4 vectorized)
// blocks [8192,8704): beta -> betaT (bf16, LDS 32x32 tiles)
// blocks [8704,9216): eta  -> etaT  (bf16, LDS 32x32 tiles)
// block 9216: p,q from logits
__global__ void prep_cvt_kernel(const float* __restrict__ emb,
                                ushort* __restrict__ a16,
                                const float* __restrict__ beta,
                                const float* __restrict__ eta,
                                const float* __restrict__ la,
                                const float* __restrict__ ld,
                                ushort* __restrict__ betaT,
                                ushort* __restrict__ etaT,
                                float* __restrict__ p,
                                float* __restrict__ q) {
    __shared__ float tf[32][33];
    int blk = blockIdx.x;
    if (blk < 8192) {
        int i = blk * 256 + threadIdx.x;     // one per 4 floats
        float4 v = ((const float4*)emb)[i];
        ushort4 o;
        o.x = f2b(v.x); o.y = f2b(v.y); o.z = f2b(v.z); o.w = f2b(v.w);
        ((ushort4*)a16)[i] = o;
    } else if (blk < 8704) {                 // beta transpose
        int tile = blk - 8192;
        int tr = tile >> 5, tc = tile & 31;
        int r = threadIdx.x >> 3, c4 = (threadIdx.x & 7) * 4;
        float4 v = *(const float4*)(beta + (size_t)(tr * 32 + r) * EDIM + tc * 32 + c4);
        tf[r][c4 + 0] = v.x; tf[r][c4 + 1] = v.y;
        tf[r][c4 + 2] = v.z; tf[r][c4 + 3] = v.w;
        __syncthreads();
        ushort4 o;
        o.x = f2b(tf[c4 + 0][r]); o.y = f2b(tf[c4 + 1][r]);
        o.z = f2b(tf[c4 + 2][r]); o.w = f2b(tf[c4 + 3][r]);
        *(ushort4*)(betaT + (size_t)(tc * 32 + r) * DIM + tr * 32 + c4) = o;
    } else if (blk < 9216) {                 // eta transpose
        int tile = blk - 8704;
        int tr = tile >> 4, tc = tile & 15;
        int r = threadIdx.x >> 3, c4 = (threadIdx.x & 7) * 4;
        float4 v = *(const float4*)(eta + (size_t)(tr * 32 + r) * OUTD + tc * 32 + c4);
        tf[r][c4 + 0] = v.x; tf[r][c4 + 1] = v.y;
        tf[r][c4 + 2] = v.z; tf[r][c4 + 3] = v.w;
        __syncthreads();
        ushort4 o;
        o.x = f2b(tf[c4 + 0][r]); o.y = f2b(tf[c4 + 1][r]);
        o.z = f2b(tf[c4 + 2][r]); o.w = f2b(tf[c4 + 3][r]);
        *(ushort4*)(etaT + (size_t)(tc * 32 + r) * EDIM + tr * 32 + c4) = o;
    } else {
        #pragma unroll
        for (int j = 0; j < 4; ++j) {
            int e = threadIdx.x * 4 + j;
            float a = sigmoidf(la[e]);
            float d = sigmoidf(ld[e]);
            p[e] = a;
            q[e] = 1.0f - a * d;
        }
    }
}

// ---------------- GEMM1 + scan (cooperative): 256x256 4-phase (R5 loop) ---
// Hot loop identical to R5's measured-best gemm256. Epilogue: compute agg,
// threadfence + grid.sync, compose carries from agg (q^64 Horner), apply the
// within-chunk suffix EMA to the in-register acc, write u' once (bf16).
// Eliminates the scan kernel + raw-u round trip.
#define MFMA_BF16 __builtin_amdgcn_mfma_f32_16x16x32_bf16

__global__ __launch_bounds__(512, 1) void gemm1_coop(
        const ushort* __restrict__ A, const ushort* __restrict__ Bt,
        ushort* __restrict__ Cv, const float* __restrict__ qv,
        const float* __restrict__ pv, float* __restrict__ aggp) {
    extern __shared__ __align__(16) char smem[];   // 131072 bytes
    const int tid  = threadIdx.x;
    const int lane = tid & 63;
    const int wid  = tid >> 6;       // 0..7
    const int wr   = wid >> 2;       // 0..1  (M half)
    const int wc   = wid & 3;        // 0..3  (N quarter)
    const int l15  = lane & 15;
    const int l4   = lane >> 4;

    const int nwg  = gridDim.x;      // 256
    const int flat = ((int)blockIdx.x & 7) * (nwg >> 3) + ((int)blockIdx.x >> 3);
    const int rowBase = (flat >> 2) << 8;
    const int colBase = (flat & 3) << 8;

    const int row0  = tid >> 3;                 // 0..63, +64 per i
    const int col16 = (tid & 7) ^ (row0 & 7);   // pre-swizzled source column
    const ushort* gA0 = A  + (size_t)(rowBase + row0) * DIM + col16 * 8;
    const ushort* gB0 = Bt + (size_t)(colBase + row0) * DIM + col16 * 8;
    const int ldsOff = tid * 16;

    const int sw   = (l15 & 7) << 4;
    const int aRow = (wr * 128 + l15) * 128;
    const int bRow = 32768 + (wc * 64 + l15) * 128;
    const int a0 = aRow + ((l4 * 16) ^ sw);
    const int a1 = aRow + ((64 + l4 * 16) ^ sw);
    const int b0 = bRow + ((l4 * 16) ^ sw);
    const int b1 = bRow + ((64 + l4 * 16) ^ sw);

    f32x4 acc[8][4] = {};
    bf16x8 af[4][2], bfr[4][2];

    const int NT = DIM >> 6;   // 8

    auto STAGE = [&](int t) {
        const int boff = (t & 1) << 16;
        const size_t koff = (size_t)t * 64;
        #pragma unroll
        for (int i = 0; i < 4; ++i)
            __builtin_amdgcn_global_load_lds(
                (const __attribute__((address_space(1))) void*)(gA0 + (size_t)i * 64 * DIM + koff),
                (__attribute__((address_space(3))) void*)(smem + boff + i * 8192 + ldsOff),
                16, 0, 0);
        #pragma unroll
        for (int i = 0; i < 4; ++i)
            __builtin_amdgcn_global_load_lds(
                (const __attribute__((address_space(1))) void*)(gB0 + (size_t)i * 64 * DIM + koff),
                (__attribute__((address_space(3))) void*)(smem + boff + 32768 + i * 8192 + ldsOff),
                16, 0, 0);
    };

    STAGE(0);
    asm volatile("s_waitcnt vmcnt(0)" ::: "memory");
    __builtin_amdgcn_s_barrier();

    for (int t = 0; t < NT; ++t) {
        const char* sm = smem + ((t & 1) << 16);
        if (t + 1 < NT) STAGE(t + 1);
        // ---- phase 1: read A[m0-3], B[n0-1]; MFMA ----
        #pragma unroll
        for (int m = 0; m < 4; ++m) {
            af[m][0] = *(const bf16x8*)(sm + a0 + m * 2048);
            af[m][1] = *(const bf16x8*)(sm + a1 + m * 2048);
        }
        #pragma unroll
        for (int n = 0; n < 2; ++n) {
            bfr[n][0] = *(const bf16x8*)(sm + b0 + n * 2048);
            bfr[n][1] = *(const bf16x8*)(sm + b1 + n * 2048);
        }
        __builtin_amdgcn_s_barrier();
        __builtin_amdgcn_s_setprio(1);
        #pragma unroll
        for (int m = 0; m < 4; ++m)
            #pragma unroll
            for (int n = 0; n < 2; ++n) {
                acc[m][n] = MFMA_BF16(af[m][0], bfr[n][0], acc[m][n], 0, 0, 0);
                acc[m][n] = MFMA_BF16(af[m][1], bfr[n][1], acc[m][n], 0, 0, 0);
            }
        __builtin_amdgcn_s_setprio(0);
        __builtin_amdgcn_s_barrier();
        // ---- phase 2: read B[n2-3]; MFMA ----
        #pragma unroll
        for (int n = 2; n < 4; ++n) {
            bfr[n][0] = *(const bf16x8*)(sm + b0 + n * 2048);
            bfr[n][1] = *(const bf16x8*)(sm + b1 + n * 2048);
        }
        __builtin_amdgcn_s_barrier();
        __builtin_amdgcn_s_setprio(1);
        #pragma unroll
        for (int m = 0; m < 4; ++m)
            #pragma unroll
            for (int n = 2; n < 4; ++n) {
                acc[m][n] = MFMA_BF16(af[m][0], bfr[n][0], acc[m][n], 0, 0, 0);
                acc[m][n] = MFMA_BF16(af[m][1], bfr[n][1], acc[m][n], 0, 0, 0);
            }
        __builtin_amdgcn_s_setprio(0);
        __builtin_amdgcn_s_barrier();
        // ---- phase 3: read A[m4-7]; MFMA m4-7 x n0-1 ----
        #pragma unroll
        for (int m = 0; m < 4; ++m) {
            af[m][0] = *(const bf16x8*)(sm + a0 + (m + 4) * 2048);
            af[m][1] = *(const bf16x8*)(sm + a1 + (m + 4) * 2048);
        }
        __builtin_amdgcn_s_barrier();
        __builtin_amdgcn_s_setprio(1);
        #pragma unroll
        for (int m = 0; m < 4; ++m)
            #pragma unroll
            for (int n = 0; n < 2; ++n) {
                acc[m + 4][n] = MFMA_BF16(af[m][0], bfr[n][0], acc[m + 4][n], 0, 0, 0);
                acc[m + 4][n] = MFMA_BF16(af[m][1], bfr[n][1], acc[m + 4][n], 0, 0, 0);
            }
        __builtin_amdgcn_s_setprio(0);
        __builtin_amdgcn_s_barrier();
        // ---- phase 4: MFMA m4-7 x n2-3; drain; barrier ----
        __builtin_amdgcn_s_setprio(1);
        #pragma unroll
        for (int m = 0; m < 4; ++m)
            #pragma unroll
            for (int n = 2; n < 4; ++n) {
                acc[m + 4][n] = MFMA_BF16(af[m][0], bfr[n][0], acc[m + 4][n], 0, 0, 0);
                acc[m + 4][n] = MFMA_BF16(af[m][1], bfr[n][1], acc[m + 4][n], 0, 0, 0);
            }
        __builtin_amdgcn_s_setprio(0);
        asm volatile("s_waitcnt vmcnt(0)" ::: "memory");
        __builtin_amdgcn_s_barrier();
    }

    // ================= epilogue: agg -> grid sync -> scan-apply ===========
    const int bidx      = rowBase >> 12;
    const int chunkBase = ((rowBase & 4095) >> 6) + wr * 2;   // h chunk = +h

    // ---- phase A: 16-row block sums B[h][n][g]; agg per chunk ----
    float Bv[2][4][4];
    #pragma unroll
    for (int h = 0; h < 2; ++h) {
        #pragma unroll
        for (int n = 0; n < 4; ++n) {
            int col = colBase + wc * 64 + n * 16 + l15;
            float qe = qv[col];
            float q2 = qe * qe, q4 = q2 * q2, q8 = q4 * q4, q16 = q8 * q8;
            float ql4 = (l4 & 1 ? q4 : 1.0f) * (l4 & 2 ? q8 : 1.0f);
            #pragma unroll
            for (int g = 0; g < 4; ++g) {
                f32x4 a = acc[h * 4 + g][n];
                float seg = ((a[3] * qe + a[2]) * qe + a[1]) * qe + a[0];
                float v = seg * ql4;
                v += __shfl_xor(v, 16, 64);
                v += __shfl_xor(v, 32, 64);
                Bv[h][n][g] = v;                   // all lanes: 16-row sum
            }
            float aggv = ((Bv[h][n][3] * q16 + Bv[h][n][2]) * q16
                          + Bv[h][n][1]) * q16 + Bv[h][n][0];
            if (l4 == 0)
                aggp[(((bidx << 6) | (chunkBase + h)) << 10) + col] = aggv;
        }
    }
    __threadfence();
    cg::this_grid().sync();

    // ---- phase B: carries + within-chunk suffix apply, write u' ----
    #pragma unroll
    for (int n = 0; n < 4; ++n) {
        int col = colBase + wc * 64 + n * 16 + l15;
        float qe = qv[col], pe = pv[col];
        float q2 = qe * qe, q4 = q2 * q2, q8 = q4 * q4, q16 = q8 * q8;
        float q12 = q4 * q8;
        float qL = q16 * q16; qL = qL * qL;        // q^64
        // carry for chunk (chunkBase+1): downward Horner over agg rows
        float carry1 = 0.0f;
        for (int cp = 63; cp >= chunkBase + 2; --cp)
            carry1 = aggp[(((bidx << 6) | cp) << 10) + col] + qL * carry1;
        float carry0 = aggp[(((bidx << 6) | (chunkBase + 1)) << 10) + col]
                       + qL * carry1;
        #pragma unroll
        for (int h = 0; h < 2; ++h) {
            float carry = h ? carry1 : carry0;
            // T-chain: Tn[g] = S at start of 16-block g+1
            float Tn[4];
            Tn[3] = carry;
            Tn[2] = Bv[h][n][3] + q16 * Tn[3];
            Tn[1] = Bv[h][n][2] + q16 * Tn[2];
            Tn[0] = Bv[h][n][1] + q16 * Tn[1];
            #pragma unroll
            for (int g = 0; g < 4; ++g) {
                f32x4 a = acc[h * 4 + g][n];
                float seg = ((a[3] * qe + a[2]) * qe + a[1]) * qe + a[0];
                // cross-l4 suffix of segment sums (weights q^4d)
                float s16 = __shfl(seg, lane + 16, 64);
                float s32 = __shfl(seg, lane + 32, 64);
                float s48 = __shfl(seg, lane + 48, 64);
                float suf = seg
                          + (l4 <= 2 ? q4  * s16 : 0.0f)
                          + (l4 <= 1 ? q8  * s32 : 0.0f)
                          + (l4 == 0 ? q12 * s48 : 0.0f);
                float fac = (l4 == 0) ? q16 : (l4 == 1) ? q12
                          : (l4 == 2) ? q8  : q4;       // q^(16-4*l4)
                float S0 = suf + fac * Tn[g];           // S at own seg start
                float Sn4 = __shfl(S0, lane + 16, 64);  // S at next seg start
                if (l4 == 3) Sn4 = Tn[g];
                float S3 = a[3] + qe * Sn4;
                float S2 = a[2] + qe * S3;
                float S1 = a[1] + qe * S2;
                float S0b = a[0] + qe * S1;
                int row = rowBase + wr * 128 + (h * 4 + g) * 16 + l4 * 4;
                ushort* dst = Cv + (size_t)row * EDIM + col;
                dst[0 * EDIM] = f2b(pe * S0b);
                dst[1 * EDIM] = f2b(pe * S1);
                dst[2 * EDIM] = f2b(pe * S2);
                dst[3 * EDIM] = f2b(pe * S3);
            }
        }
    }
}

// ------------------------------- GEMM2: 128x128 m97 structure (R5) --------
template <int OUT_BF16>
__global__ __launch_bounds__(256) void gemm_bt(const ushort* __restrict__ A,
                                               const ushort* __restrict__ Bt,
                                               void* __restrict__ Cv,
                                               int M, int N, int K,
                                               int ncolShift) {
    __shared__ ushort smem[16384];
    const int tid  = threadIdx.x;
    const int lane = tid & 63;
    const int wid  = tid >> 6;
    const int wr   = wid >> 1, wc = wid & 1;
    const int l15  = lane & 15;
    const int l4   = lane >> 4;

    const int nwg   = gridDim.x;
    const int chunkw = nwg >> 3;
    const int flat  = (blockIdx.x & 7) * chunkw + (blockIdx.x >> 3);
    const int rowBase = (flat >> ncolShift) << 7;
    const int colBase = (flat & ((1 << ncolShift) - 1)) << 7;

    f32x4 acc[4][4] = {};

    const int nkb = K >> 6;
    for (int kb = 0; kb < nkb; ++kb) {
        #pragma unroll
        for (int r = 0; r < 4; ++r) {
            int c     = r * 256 + tid;
            int row   = c >> 3;
            int col16 = (c & 7) ^ (row & 7);
            const ushort* ga = A  + (size_t)(rowBase + row) * K + kb * 64 + col16 * 8;
            __builtin_amdgcn_global_load_lds(
                (const __attribute__((address_space(1))) void*)ga,
                (__attribute__((address_space(3))) void*)((char*)smem + c * 16),
                16, 0, 0);
            const ushort* gb = Bt + (size_t)(colBase + row) * K + kb * 64 + col16 * 8;
            __builtin_amdgcn_global_load_lds(
                (const __attribute__((address_space(1))) void*)gb,
                (__attribute__((address_space(3))) void*)((char*)smem + 16384 + c * 16),
                16, 0, 0);
        }
        __syncthreads();

        #pragma unroll
        for (int kk = 0; kk < 2; ++kk) {
            bf16x8 af[4], bfr[4];
            #pragma unroll
            for (int m = 0; m < 4; ++m) {
                int row   = wr * 64 + m * 16 + l15;
                int kbyte = kk * 64 + l4 * 16;
                int addr  = row * 128 + (kbyte ^ ((row & 7) << 4));
                af[m] = *(const bf16x8*)((const char*)smem + addr);
            }
            #pragma unroll
            for (int n = 0; n < 4; ++n) {
                int row   = wc * 64 + n * 16 + l15;
                int kbyte = kk * 64 + l4 * 16;
                int addr  = 16384 + row * 128 + (kbyte ^ ((row & 7) << 4));
                bfr[n] = *(const bf16x8*)((const char*)smem + addr);
            }
            #pragma unroll
            for (int m = 0; m < 4; ++m)
                #pragma unroll
                for (int n = 0; n < 4; ++n)
                    acc[m][n] = __builtin_amdgcn_mfma_f32_16x16x32_bf16(
                        af[m], bfr[n], acc[m][n], 0, 0, 0);
        }
        __syncthreads();
    }

    #pragma unroll
    for (int m = 0; m < 4; ++m)
        #pragma unroll
        for (int n = 0; n < 4; ++n)
            #pragma unroll
            for (int r = 0; r < 4; ++r) {
                int row = rowBase + wr * 64 + m * 16 + l4 * 4 + r;
                int col = colBase + wc * 64 + n * 16 + l15;
                if (OUT_BF16)
                    ((ushort*)Cv)[(size_t)row * N + col] = f2b(acc[m][n][r]);
                else
                    ((float*)Cv)[(size_t)row * N + col] = acc[m][n][r];
            }
}

// -------------------------------------------------------------- launch ----
extern "C" void kernel_launch(void* const* d_in, const int* in_sizes, int n_in,
                              void* d_out, int out_size, void* d_ws, size_t ws_size,
                              hipStream_t stream) {
    const float* emb  = (const float*)d_in[0];
    const float* la   = (const float*)d_in[1];
    const float* ld   = (const float*)d_in[2];
    const float* beta = (const float*)d_in[3];
    const float* eta  = (const float*)d_in[4];

    char* ws = (char*)d_ws;
    ushort* a16   = (ushort*)(ws);                    // 16 MB  emb bf16
    ushort* betaT = (ushort*)(ws + 16777216);         // 1 MB
    ushort* etaT  = (ushort*)(ws + 17825792);         // 1 MB
    ushort* u     = (ushort*)(ws + 18874368);         // 32 MB  u' (scanned)
    float*  p     = (float*) (ws + 52428800);         // 4 KB
    float*  q     = (float*) (ws + 52432896);         // 4 KB
    float*  agg   = (float*) (ws + 52436992);         // 1 MB [4][64][1024]

    (void)hipFuncSetAttribute((const void*)gemm1_coop,
                              hipFuncAttributeMaxDynamicSharedMemorySize, 131072);

    prep_cvt_kernel<<<dim3(9217), dim3(256), 0, stream>>>(
        emb, a16, beta, eta, la, ld, betaT, etaT, p, q);

    // u'[16384,1024] = suffix-EMA( emb_bf16 @ betaT^T )  (cooperative)
    {
        const ushort* A_ = a16; const ushort* B_ = betaT; ushort* C_ = u;
        const float* q_ = q; const float* p_ = p; float* g_ = agg;
        void* args[] = { (void*)&A_, (void*)&B_, (void*)&C_,
                         (void*)&q_, (void*)&p_, (void*)&g_ };
        (void)hipLaunchCooperativeKernel((const void*)gemm1_coop,
                                         dim3(256), dim3(512),
                                         args, 131072, stream);
    }

    // y[16384,512] = u' @ etaT^T   (128^2, fp32 out)
    gemm_bt<0><<<dim3((MROWS / 128) * (OUTD / 128)), dim3(256), 0, stream>>>(
        u, etaT, d_out, MROWS, OUTD, EDIM, 2);
}

// Round 11
// 80.233 us; speedup vs baseline: 2.2753x; 2.2753x over previous
//
#include <hip/hip_runtime.h>
#include <hip/hip_bf16.h>

#define DIM      512
#define EDIM     1024
#define OUTD     512
#define BATCH    4
#define LSEQ     4096
#define MROWS    (BATCH * LSEQ)   // 16384
#define NCHUNK   64
#define CHUNK    (LSEQ / NCHUNK)  // 64

typedef __attribute__((ext_vector_type(8))) __bf16 bf16x8;
typedef __attribute__((ext_vector_type(4))) float  f32x4;

static __device__ __forceinline__ ushort f2b(float f) {
    uint x = __float_as_uint(f);
    x += 0x7fff + ((x >> 16) & 1);           // round-to-nearest-even
    return (ushort)(x >> 16);
}
static __device__ __forceinline__ float b2f(ushort u) {
    return __uint_as_float(((uint)u) << 16);
}
static __device__ __forceinline__ float sigmoidf(float x) {
    return 1.0f / (1.0f + expf(-x));
}

// ------------------------------------------------- prep + emb->bf16 -------
// blocks [0,8192): convert emb fp32 -> bf16 (float4 vectorized)
// blocks [8192,8704): beta -> betaT (bf16, LDS 32x32 tiles)
// blocks [8704,9216): eta  -> etaT  (bf16, LDS 32x32 tiles)
// block 9216: p,q from logits
__global__ void prep_cvt_kernel(const float* __restrict__ emb,
                                ushort* __restrict__ a16,
                                const float* __restrict__ beta,
                                const float* __restrict__ eta,
                                const float* __restrict__ la,
                                const float* __restrict__ ld,
                                ushort* __restrict__ betaT,
                                ushort* __restrict__ etaT,
                                float* __restrict__ p,
                                float* __restrict__ q) {
    __shared__ float tf[32][33];
    int blk = blockIdx.x;
    if (blk < 8192) {
        int i = blk * 256 + threadIdx.x;     // one per 4 floats
        float4 v = ((const float4*)emb)[i];
        ushort4 o;
        o.x = f2b(v.x); o.y = f2b(v.y); o.z = f2b(v.z); o.w = f2b(v.w);
        ((ushort4*)a16)[i] = o;
    } else if (blk < 8704) {                 // beta transpose
        int tile = blk - 8192;
        int tr = tile >> 5, tc = tile & 31;
        int r = threadIdx.x >> 3, c4 = (threadIdx.x & 7) * 4;
        float4 v = *(const float4*)(beta + (size_t)(tr * 32 + r) * EDIM + tc * 32 + c4);
        tf[r][c4 + 0] = v.x; tf[r][c4 + 1] = v.y;
        tf[r][c4 + 2] = v.z; tf[r][c4 + 3] = v.w;
        __syncthreads();
        ushort4 o;
        o.x = f2b(tf[c4 + 0][r]); o.y = f2b(tf[c4 + 1][r]);
        o.z = f2b(tf[c4 + 2][r]); o.w = f2b(tf[c4 + 3][r]);
        *(ushort4*)(betaT + (size_t)(tc * 32 + r) * DIM + tr * 32 + c4) = o;
    } else if (blk < 9216) {                 // eta transpose
        int tile = blk - 8704;
        int tr = tile >> 4, tc = tile & 15;
        int r = threadIdx.x >> 3, c4 = (threadIdx.x & 7) * 4;
        float4 v = *(const float4*)(eta + (size_t)(tr * 32 + r) * OUTD + tc * 32 + c4);
        tf[r][c4 + 0] = v.x; tf[r][c4 + 1] = v.y;
        tf[r][c4 + 2] = v.z; tf[r][c4 + 3] = v.w;
        __syncthreads();
        ushort4 o;
        o.x = f2b(tf[c4 + 0][r]); o.y = f2b(tf[c4 + 1][r]);
        o.z = f2b(tf[c4 + 2][r]); o.w = f2b(tf[c4 + 3][r]);
        *(ushort4*)(etaT + (size_t)(tc * 32 + r) * EDIM + tr * 32 + c4) = o;
    } else {
        #pragma unroll
        for (int j = 0; j < 4; ++j) {
            int e = threadIdx.x * 4 + j;
            float a = sigmoidf(la[e]);
            float d = sigmoidf(ld[e]);
            p[e] = a;
            q[e] = 1.0f - a * d;
        }
    }
}

// ------------------------------------------- GEMM 256x256 4-phase ---------
// C[M,N] = A[M,K]*Bt[N,K]^T. BM=BN=256, BK=64, 8 waves (2Mx4N), per-wave
// 128x64. 2 K-tile LDS buffers (128 KB dynamic). Stage t+1 at top of tile t,
// drain once per tile just before last barrier (64 MFMA/wave of cover).
#define MFMA_BF16 __builtin_amdgcn_mfma_f32_16x16x32_bf16
template <int KDIM, int NSHIFT, int OUT_BF16, int DO_AGG>
__global__ __launch_bounds__(512, 2) void gemm256(const ushort* __restrict__ A,
                                                  const ushort* __restrict__ Bt,
                                                  void* __restrict__ Cv,
                                                  const float* __restrict__ qv,
                                                  float* __restrict__ aggp,
                                                  int N) {
    extern __shared__ __align__(16) char smem[];   // 131072 bytes
    const int tid  = threadIdx.x;
    const int lane = tid & 63;
    const int wid  = tid >> 6;       // 0..7
    const int wr   = wid >> 2;       // 0..1  (M half)
    const int wc   = wid & 3;        // 0..3  (N quarter)
    const int l15  = lane & 15;
    const int l4   = lane >> 4;

    const int nwg  = gridDim.x;      // multiple of 8
    const int flat = ((int)blockIdx.x & 7) * (nwg >> 3) + ((int)blockIdx.x >> 3);
    const int rowBase = (flat >> NSHIFT) << 8;
    const int colBase = (flat & ((1 << NSHIFT) - 1)) << 8;

    const int row0  = tid >> 3;                 // 0..63, +64 per i
    const int col16 = (tid & 7) ^ (row0 & 7);   // pre-swizzled source column
    const ushort* gA0 = A  + (size_t)(rowBase + row0) * KDIM + col16 * 8;
    const ushort* gB0 = Bt + (size_t)(colBase + row0) * KDIM + col16 * 8;
    const int ldsOff = tid * 16;

    const int sw   = (l15 & 7) << 4;
    const int aRow = (wr * 128 + l15) * 128;
    const int bRow = 32768 + (wc * 64 + l15) * 128;
    const int a0 = aRow + ((l4 * 16) ^ sw);
    const int a1 = aRow + ((64 + l4 * 16) ^ sw);
    const int b0 = bRow + ((l4 * 16) ^ sw);
    const int b1 = bRow + ((64 + l4 * 16) ^ sw);

    f32x4 acc[8][4] = {};
    bf16x8 af[4][2], bfr[4][2];

    const int NT = KDIM >> 6;

    auto STAGE = [&](int t) {
        const int boff = (t & 1) << 16;
        const size_t koff = (size_t)t * 64;
        #pragma unroll
        for (int i = 0; i < 4; ++i)
            __builtin_amdgcn_global_load_lds(
                (const __attribute__((address_space(1))) void*)(gA0 + (size_t)i * 64 * KDIM + koff),
                (__attribute__((address_space(3))) void*)(smem + boff + i * 8192 + ldsOff),
                16, 0, 0);
        #pragma unroll
        for (int i = 0; i < 4; ++i)
            __builtin_amdgcn_global_load_lds(
                (const __attribute__((address_space(1))) void*)(gB0 + (size_t)i * 64 * KDIM + koff),
                (__attribute__((address_space(3))) void*)(smem + boff + 32768 + i * 8192 + ldsOff),
                16, 0, 0);
    };

    STAGE(0);
    asm volatile("s_waitcnt vmcnt(0)" ::: "memory");
    __builtin_amdgcn_s_barrier();

    for (int t = 0; t < NT; ++t) {
        const char* sm = smem + ((t & 1) << 16);
        if (t + 1 < NT) STAGE(t + 1);
        // ---- phase 1: read A[m0-3], B[n0-1]; MFMA ----
        #pragma unroll
        for (int m = 0; m < 4; ++m) {
            af[m][0] = *(const bf16x8*)(sm + a0 + m * 2048);
            af[m][1] = *(const bf16x8*)(sm + a1 + m * 2048);
        }
        #pragma unroll
        for (int n = 0; n < 2; ++n) {
            bfr[n][0] = *(const bf16x8*)(sm + b0 + n * 2048);
            bfr[n][1] = *(const bf16x8*)(sm + b1 + n * 2048);
        }
        __builtin_amdgcn_s_barrier();
        __builtin_amdgcn_s_setprio(1);
        #pragma unroll
        for (int m = 0; m < 4; ++m)
            #pragma unroll
            for (int n = 0; n < 2; ++n) {
                acc[m][n] = MFMA_BF16(af[m][0], bfr[n][0], acc[m][n], 0, 0, 0);
                acc[m][n] = MFMA_BF16(af[m][1], bfr[n][1], acc[m][n], 0, 0, 0);
            }
        __builtin_amdgcn_s_setprio(0);
        __builtin_amdgcn_s_barrier();
        // ---- phase 2: read B[n2-3]; MFMA ----
        #pragma unroll
        for (int n = 2; n < 4; ++n) {
            bfr[n][0] = *(const bf16x8*)(sm + b0 + n * 2048);
            bfr[n][1] = *(const bf16x8*)(sm + b1 + n * 2048);
        }
        __builtin_amdgcn_s_barrier();
        __builtin_amdgcn_s_setprio(1);
        #pragma unroll
        for (int m = 0; m < 4; ++m)
            #pragma unroll
            for (int n = 2; n < 4; ++n) {
                acc[m][n] = MFMA_BF16(af[m][0], bfr[n][0], acc[m][n], 0, 0, 0);
                acc[m][n] = MFMA_BF16(af[m][1], bfr[n][1], acc[m][n], 0, 0, 0);
            }
        __builtin_amdgcn_s_setprio(0);
        __builtin_amdgcn_s_barrier();
        // ---- phase 3: read A[m4-7]; MFMA m4-7 x n0-1 ----
        #pragma unroll
        for (int m = 0; m < 4; ++m) {
            af[m][0] = *(const bf16x8*)(sm + a0 + (m + 4) * 2048);
            af[m][1] = *(const bf16x8*)(sm + a1 + (m + 4) * 2048);
        }
        __builtin_amdgcn_s_barrier();
        __builtin_amdgcn_s_setprio(1);
        #pragma unroll
        for (int m = 0; m < 4; ++m)
            #pragma unroll
            for (int n = 0; n < 2; ++n) {
                acc[m + 4][n] = MFMA_BF16(af[m][0], bfr[n][0], acc[m + 4][n], 0, 0, 0);
                acc[m + 4][n] = MFMA_BF16(af[m][1], bfr[n][1], acc[m + 4][n], 0, 0, 0);
            }
        __builtin_amdgcn_s_setprio(0);
        __builtin_amdgcn_s_barrier();
        // ---- phase 4: MFMA m4-7 x n2-3; drain prefetch; barrier ----
        __builtin_amdgcn_s_setprio(1);
        #pragma unroll
        for (int m = 0; m < 4; ++m)
            #pragma unroll
            for (int n = 2; n < 4; ++n) {
                acc[m + 4][n] = MFMA_BF16(af[m][0], bfr[n][0], acc[m + 4][n], 0, 0, 0);
                acc[m + 4][n] = MFMA_BF16(af[m][1], bfr[n][1], acc[m + 4][n], 0, 0, 0);
            }
        __builtin_amdgcn_s_setprio(0);
        asm volatile("s_waitcnt vmcnt(0)" ::: "memory");
        __builtin_amdgcn_s_barrier();
    }

    // ---- C store ----
    #pragma unroll
    for (int m = 0; m < 8; ++m)
        #pragma unroll
        for (int n = 0; n < 4; ++n)
            #pragma unroll
            for (int r = 0; r < 4; ++r) {
                int row = rowBase + wr * 128 + m * 16 + l4 * 4 + r;
                int col = colBase + wc * 64 + n * 16 + l15;
                if (OUT_BF16)
                    ((ushort*)Cv)[(size_t)row * N + col] = f2b(acc[m][n][r]);
                else
                    ((float*)Cv)[(size_t)row * N + col] = acc[m][n][r];
            }

    // ---- fused per-64-row-chunk EMA aggregates (2 chunks per wave) ----
    if (DO_AGG) {
        const int bidx = rowBase >> 12;
        const int chunkBase = ((rowBase & 4095) >> 6) + wr * 2;
        #pragma unroll
        for (int h = 0; h < 2; ++h) {
            #pragma unroll
            for (int n = 0; n < 4; ++n) {
                int col = colBase + wc * 64 + n * 16 + l15;
                float qe = qv[col];
                float q2 = qe * qe, q4 = q2 * q2, q8 = q4 * q4, q16 = q8 * q8;
                float P = 0.0f;
                #pragma unroll
                for (int m = 3; m >= 0; --m) {
                    f32x4 a = acc[h * 4 + m][n];
                    float pm = ((a[3] * qe + a[2]) * qe + a[1]) * qe + a[0];
                    P = P * q16 + pm;
                }
                float ql4 = (l4 & 1 ? q4 : 1.0f) * (l4 & 2 ? q8 : 1.0f);
                P *= ql4;
                P += __shfl_xor(P, 16, 64);
                P += __shfl_xor(P, 32, 64);
                if (l4 == 0)
                    aggp[(((bidx << 6) | (chunkBase + h)) << 10) + col] = P;
            }
        }
    }
}

// ------------------------------- GEMM 128x128 (m97 structure, gemm2) ------
template <int OUT_BF16>
__global__ __launch_bounds__(256) void gemm_bt(const ushort* __restrict__ A,
                                               const ushort* __restrict__ Bt,
                                               void* __restrict__ Cv,
                                               int M, int N, int K,
                                               int ncolShift) {
    __shared__ ushort smem[16384];
    const int tid  = threadIdx.x;
    const int lane = tid & 63;
    const int wid  = tid >> 6;
    const int wr   = wid >> 1, wc = wid & 1;
    const int l15  = lane & 15;
    const int l4   = lane >> 4;

    const int nwg   = gridDim.x;
    const int chunkw = nwg >> 3;
    const int flat  = (blockIdx.x & 7) * chunkw + (blockIdx.x >> 3);
    const int rowBase = (flat >> ncolShift) << 7;
    const int colBase = (flat & ((1 << ncolShift) - 1)) << 7;

    f32x4 acc[4][4] = {};

    const int nkb = K >> 6;
    for (int kb = 0; kb < nkb; ++kb) {
        #pragma unroll
        for (int r = 0; r < 4; ++r) {
            int c     = r * 256 + tid;
            int row   = c >> 3;
            int col16 = (c & 7) ^ (row & 7);
            const ushort* ga = A  + (size_t)(rowBase + row) * K + kb * 64 + col16 * 8;
            __builtin_amdgcn_global_load_lds(
                (const __attribute__((address_space(1))) void*)ga,
                (__attribute__((address_space(3))) void*)((char*)smem + c * 16),
                16, 0, 0);
            const ushort* gb = Bt + (size_t)(colBase + row) * K + kb * 64 + col16 * 8;
            __builtin_amdgcn_global_load_lds(
                (const __attribute__((address_space(1))) void*)gb,
                (__attribute__((address_space(3))) void*)((char*)smem + 16384 + c * 16),
                16, 0, 0);
        }
        __syncthreads();

        #pragma unroll
        for (int kk = 0; kk < 2; ++kk) {
            bf16x8 af[4], bfr[4];
            #pragma unroll
            for (int m = 0; m < 4; ++m) {
                int row   = wr * 64 + m * 16 + l15;
                int kbyte = kk * 64 + l4 * 16;
                int addr  = row * 128 + (kbyte ^ ((row & 7) << 4));
                af[m] = *(const bf16x8*)((const char*)smem + addr);
            }
            #pragma unroll
            for (int n = 0; n < 4; ++n) {
                int row   = wc * 64 + n * 16 + l15;
                int kbyte = kk * 64 + l4 * 16;
                int addr  = 16384 + row * 128 + (kbyte ^ ((row & 7) << 4));
                bfr[n] = *(const bf16x8*)((const char*)smem + addr);
            }
            #pragma unroll
            for (int m = 0; m < 4; ++m)
                #pragma unroll
                for (int n = 0; n < 4; ++n)
                    acc[m][n] = __builtin_amdgcn_mfma_f32_16x16x32_bf16(
                        af[m], bfr[n], acc[m][n], 0, 0, 0);
        }
        __syncthreads();
    }

    #pragma unroll
    for (int m = 0; m < 4; ++m)
        #pragma unroll
        for (int n = 0; n < 4; ++n)
            #pragma unroll
            for (int r = 0; r < 4; ++r) {
                int row = rowBase + wr * 64 + m * 16 + l4 * 4 + r;
                int col = colBase + wc * 64 + n * 16 + l15;
                if (OUT_BF16)
                    ((ushort*)Cv)[(size_t)row * N + col] = f2b(acc[m][n][r]);
                else
                    ((float*)Cv)[(size_t)row * N + col] = acc[m][n][r];
            }
}

// ---------------------------------------------------------------- scan ----
// In-place suffix EMA apply with cross-chunk carry from agg. 2 ch/thread,
// 512 blocks (2 blocks/CU -> 2 waves/SIMD TLP for the latency chain).
__global__ void scan_apply_kernel(ushort* __restrict__ u,
                                  const float* __restrict__ pv,
                                  const float* __restrict__ qv,
                                  const float* __restrict__ agg) {
    int t = blockIdx.x * blockDim.x + threadIdx.x;   // 131072
    int e0 = (t & 511) * 2;
    int c  = (t >> 9) & 63;
    int b  = t >> 15;
    float2 qe2 = *(const float2*)(qv + e0);
    float2 pe2 = *(const float2*)(pv + e0);
    float qe[2] = {qe2.x, qe2.y};
    float pe[2] = {pe2.x, pe2.y};
    float qL[2], S[2], w[2];
    #pragma unroll
    for (int k = 0; k < 2; ++k) {
        float x = qe[k];
        #pragma unroll
        for (int s = 0; s < 6; ++s) x *= x;    // q^64
        qL[k] = x; S[k] = 0.0f; w[k] = 1.0f;
    }
    for (int cp = c + 1; cp < NCHUNK; ++cp) {
        float2 a = *(const float2*)(agg + (((b << 6) | cp) << 10) + e0);
        S[0] += w[0] * a.x;  w[0] *= qL[0];
        S[1] += w[1] * a.y;  w[1] *= qL[1];
    }
    ushort* up = u + ((size_t)(b * LSEQ + c * CHUNK) << 10) + e0;
    #pragma unroll 4
    for (int j = CHUNK - 1; j >= 0; --j) {
        ushort2 uv = *(ushort2*)(up + (size_t)j * EDIM);
        S[0] = b2f(uv.x) + qe[0] * S[0];
        S[1] = b2f(uv.y) + qe[1] * S[1];
        ushort2 ov;
        ov.x = f2b(pe[0] * S[0]);
        ov.y = f2b(pe[1] * S[1]);
        *(ushort2*)(up + (size_t)j * EDIM) = ov;
    }
}

// -------------------------------------------------------------- launch ----
extern "C" void kernel_launch(void* const* d_in, const int* in_sizes, int n_in,
                              void* d_out, int out_size, void* d_ws, size_t ws_size,
                              hipStream_t stream) {
    const float* emb  = (const float*)d_in[0];
    const float* la   = (const float*)d_in[1];
    const float* ld   = (const float*)d_in[2];
    const float* beta = (const float*)d_in[3];
    const float* eta  = (const float*)d_in[4];

    char* ws = (char*)d_ws;
    ushort* a16   = (ushort*)(ws);                    // 16 MB  emb bf16
    ushort* betaT = (ushort*)(ws + 16777216);         // 1 MB
    ushort* etaT  = (ushort*)(ws + 17825792);         // 1 MB
    ushort* u     = (ushort*)(ws + 18874368);         // 32 MB  u (in-place out)
    float*  p     = (float*) (ws + 52428800);         // 4 KB
    float*  q     = (float*) (ws + 52432896);         // 4 KB
    float*  agg   = (float*) (ws + 52436992);         // 1 MB [4][64][1024]

    (void)hipFuncSetAttribute((const void*)gemm256<512, 2, 1, 1>,
                              hipFuncAttributeMaxDynamicSharedMemorySize, 131072);

    prep_cvt_kernel<<<dim3(9217), dim3(256), 0, stream>>>(
        emb, a16, beta, eta, la, ld, betaT, etaT, p, q);

    // u[16384,1024] = emb_bf16 @ betaT^T   (256x256 4-phase, fused agg)
    gemm256<512, 2, 1, 1><<<dim3(256), dim3(512), 131072, stream>>>(
        a16, betaT, (void*)u, q, agg, EDIM);

    scan_apply_kernel<<<dim3(512), dim3(256), 0, stream>>>(u, p, q, agg);

    // y[16384,512] = u' @ etaT^T   (128x128 structure, fp32 out)
    gemm_bt<0><<<dim3((MROWS / 128) * (OUTD / 128)), dim3(256), 0, stream>>>(
        u, etaT, d_out, MROWS, OUTD, EDIM, 2);
}